// Round 9
// baseline (214.388 us; speedup 1.0000x reference)
//
#include <hip/hip_runtime.h>
#include <math.h>

// Problem constants (fixed by the reference)
#define NN 131072
#define KK 1024
#define DD 64
#define GAMMA 0.99f
#define ALPHA 1e-9f
#define BETA 0.25f

typedef float f32x4 __attribute__((ext_vector_type(4)));
typedef short bf16x8 __attribute__((ext_vector_type(8)));

__device__ __constant__ float OMG = (float)(1.0 - 0.99);

// split fp32 -> hi (truncated bf16) + lo (RNE bf16 of residual)
__device__ __forceinline__ void split_bf16(float v, unsigned short& h, unsigned short& l) {
    unsigned int b = __float_as_uint(v);
    unsigned int hb = b & 0xFFFF0000u;
    h = (unsigned short)(hb >> 16);
    float r = v - __uint_as_float(hb);
    unsigned int lb = __float_as_uint(r);
    lb += 0x7FFFu + ((lb >> 16) & 1u);
    l = (unsigned short)(lb >> 16);
}

// ---------------------------------------------------------------------------
// Prep: build E B-fragments in MFMA layout (hi/lo split) + esqh = -|e|^2/2.
// Tile nt (16 codes) = 4 KB: [hi-k0][lo-k0][hi-k1][lo-k1], each 1 KB
// (lane l holds 16 B at frag_base + l*16).
// ---------------------------------------------------------------------------
__global__ __launch_bounds__(64)
void vq_prep(const float* __restrict__ E, float4* __restrict__ Efrag,
             float* __restrict__ esqh) {
    int nt = blockIdx.x;
    int l = threadIdx.x;
    int n = nt * 16 + (l & 15);
    int kb = (l >> 4) * 8;
    float ss = 0.f;
    #pragma unroll
    for (int ks = 0; ks < 2; ++ks) {
        const float4* xp = (const float4*)(E + (size_t)n * DD + ks * 32 + kb);
        float4 a = xp[0], b = xp[1];
        float v[8] = {a.x, a.y, a.z, a.w, b.x, b.y, b.z, b.w};
        union { float4 f; unsigned short u[8]; } H, L;
        #pragma unroll
        for (int j = 0; j < 8; ++j) {
            unsigned short hh, ll;
            split_bf16(v[j], hh, ll);
            H.u[j] = hh; L.u[j] = ll;
            ss = fmaf(v[j], v[j], ss);
        }
        int fid = nt * 4 + ks * 2;
        Efrag[(size_t)(fid + 0) * 64 + l] = H.f;   // hi-k{ks}
        Efrag[(size_t)(fid + 1) * 64 + l] = L.f;   // lo-k{ks}
    }
    ss += __shfl_xor(ss, 16, 64);
    ss += __shfl_xor(ss, 32, 64);
    if (l < 16) esqh[nt * 16 + l] = -0.5f * ss;   // MFMA C-init: score = d - esq/2
}

// ---------------------------------------------------------------------------
// Main: split-bf16 MFMA distance GEMM with LDS-staged B (m97-style K-loop).
// BM=128, 4 waves x 2 m-tiles; every wave sweeps ALL 64 col-tiles, so each
// row's argmin is wave-complete (no cross-wave reduce). B-fragments staged
// in 16KB chunks (4 tiles), register-staged double buffer, 1 barrier/chunk:
// after the barrier ds_read_b128 is resident (~12cyc) - no L2-latency
// exposure per iteration (the R6-R8 ~1000cyc/iter stall).
// ---------------------------------------------------------------------------
#define BM 128

__global__ __launch_bounds__(256, 4)
void vq_main(const float* __restrict__ X, const float* __restrict__ E,
             const float4* __restrict__ Efrag, const float* __restrict__ esqh,
             float* __restrict__ argf, float* __restrict__ mind,
             float* __restrict__ Z, int* __restrict__ cursor,
             int* __restrict__ rowlist, float* __restrict__ sumsFB,
             float* __restrict__ loss_part, int cap) {
    __shared__ float4 buf[2][1024];   // 2 x 16KB chunk (4 tiles x 4KB)
    __shared__ float esql[KK];        // 4KB
    __shared__ int bidx[BM];
    __shared__ float bsc[BM];
    __shared__ float xsqs[BM];
    __shared__ int fbflag[BM];

    int tid = threadIdx.x;
    int lane = tid & 63, w = tid >> 6;
    int lc = lane & 15, lq = lane >> 4;

    size_t bb = (size_t)blockIdx.x * BM;
    size_t R0 = bb + w * 32;          // wave w owns rows [w*32, w*32+32)

    // stage esqh (1024 floats)
    ((float4*)esql)[tid] = ((const float4*)esqh)[tid];

    // A fragments: 2 m-tiles x 2 k-steps, hi+lo (32 VGPRs) + exact xsq
    bf16x8 ah[2][2], al[2][2];
    #pragma unroll
    for (int mt = 0; mt < 2; ++mt) {
        float xq = 0.f;
        #pragma unroll
        for (int ks = 0; ks < 2; ++ks) {
            const float4* xp =
                (const float4*)(X + (R0 + mt * 16 + lc) * DD + ks * 32 + lq * 8);
            float4 x0 = xp[0], x1 = xp[1];
            float v[8] = {x0.x, x0.y, x0.z, x0.w, x1.x, x1.y, x1.z, x1.w};
            union { bf16x8 s; unsigned short u[8]; } H, L;
            #pragma unroll
            for (int j = 0; j < 8; ++j) {
                unsigned short hh, ll;
                split_bf16(v[j], hh, ll);
                H.u[j] = hh; L.u[j] = ll;
                xq = fmaf(v[j], v[j], xq);
            }
            ah[mt][ks] = H.s;
            al[mt][ks] = L.s;
        }
        xq += __shfl_xor(xq, 16, 64);
        xq += __shfl_xor(xq, 32, 64);
        if (lane < 16) xsqs[w * 32 + mt * 16 + lane] = xq;
    }

    float bestv[2][4];
    int besti[2][4];
    #pragma unroll
    for (int mt = 0; mt < 2; ++mt)
        #pragma unroll
        for (int r = 0; r < 4; ++r) { bestv[mt][r] = -3.402823466e38f; besti[mt][r] = 0; }

    // preload chunk 0 -> buf[0]
    float4 nxt[4];
    #pragma unroll
    for (int r = 0; r < 4; ++r) nxt[r] = Efrag[r * 256 + tid];
    #pragma unroll
    for (int r = 0; r < 4; ++r) buf[0][r * 256 + tid] = nxt[r];
    __syncthreads();

    for (int c = 0; c < 16; ++c) {
        int pb = c & 1;
        if (c + 1 < 16) {   // issue next chunk's global loads early
            #pragma unroll
            for (int r = 0; r < 4; ++r)
                nxt[r] = Efrag[(size_t)(c + 1) * 1024 + r * 256 + tid];
        }
        const float4* bc = buf[pb];
        #pragma unroll
        for (int t = 0; t < 4; ++t) {
            int nt = c * 4 + t;
            float ec = esql[nt * 16 + lc];
            bf16x8 bh0 = *(const bf16x8*)&bc[t * 256 + 0 * 64 + lane];
            bf16x8 bl0 = *(const bf16x8*)&bc[t * 256 + 1 * 64 + lane];
            bf16x8 bh1 = *(const bf16x8*)&bc[t * 256 + 2 * 64 + lane];
            bf16x8 bl1 = *(const bf16x8*)&bc[t * 256 + 3 * 64 + lane];

            f32x4 a0 = (f32x4){ec, ec, ec, ec};
            f32x4 a1 = (f32x4){ec, ec, ec, ec};
            a0 = __builtin_amdgcn_mfma_f32_16x16x32_bf16(ah[0][0], bh0, a0, 0, 0, 0);
            a1 = __builtin_amdgcn_mfma_f32_16x16x32_bf16(ah[1][0], bh0, a1, 0, 0, 0);
            a0 = __builtin_amdgcn_mfma_f32_16x16x32_bf16(ah[0][1], bh1, a0, 0, 0, 0);
            a1 = __builtin_amdgcn_mfma_f32_16x16x32_bf16(ah[1][1], bh1, a1, 0, 0, 0);
            a0 = __builtin_amdgcn_mfma_f32_16x16x32_bf16(ah[0][0], bl0, a0, 0, 0, 0);
            a1 = __builtin_amdgcn_mfma_f32_16x16x32_bf16(ah[1][0], bl0, a1, 0, 0, 0);
            a0 = __builtin_amdgcn_mfma_f32_16x16x32_bf16(ah[0][1], bl1, a0, 0, 0, 0);
            a1 = __builtin_amdgcn_mfma_f32_16x16x32_bf16(ah[1][1], bl1, a1, 0, 0, 0);
            a0 = __builtin_amdgcn_mfma_f32_16x16x32_bf16(al[0][0], bh0, a0, 0, 0, 0);
            a1 = __builtin_amdgcn_mfma_f32_16x16x32_bf16(al[1][0], bh0, a1, 0, 0, 0);
            a0 = __builtin_amdgcn_mfma_f32_16x16x32_bf16(al[0][1], bh1, a0, 0, 0, 0);
            a1 = __builtin_amdgcn_mfma_f32_16x16x32_bf16(al[1][1], bh1, a1, 0, 0, 0);

            int n = nt * 16 + lc;
            #pragma unroll
            for (int r = 0; r < 4; ++r) {
                if (a0[r] > bestv[0][r]) { bestv[0][r] = a0[r]; besti[0][r] = n; }
                if (a1[r] > bestv[1][r]) { bestv[1][r] = a1[r]; besti[1][r] = n; }
            }
        }
        if (c + 1 < 16) {
            #pragma unroll
            for (int r = 0; r < 4; ++r) buf[1 - pb][r * 256 + tid] = nxt[r];
            __syncthreads();
        }
    }

    // reduce across the 16 lanes holding one row (max score, low-index ties)
    #pragma unroll
    for (int off = 1; off <= 8; off <<= 1) {
        #pragma unroll
        for (int mt = 0; mt < 2; ++mt) {
            #pragma unroll
            for (int r = 0; r < 4; ++r) {
                float ov = __shfl_xor(bestv[mt][r], off, 64);
                int oi = __shfl_xor(besti[mt][r], off, 64);
                if (ov > bestv[mt][r] || (ov == bestv[mt][r] && oi < besti[mt][r])) {
                    bestv[mt][r] = ov; besti[mt][r] = oi;
                }
            }
        }
    }
    if (lc == 0) {   // wave-complete: write straight to bidx/bsc
        #pragma unroll
        for (int mt = 0; mt < 2; ++mt)
            #pragma unroll
            for (int r = 0; r < 4; ++r) {
                int row = w * 32 + mt * 16 + lq * 4 + r;
                bidx[row] = besti[mt][r];
                bsc[row] = bestv[mt][r];
            }
    }
    __syncthreads();

    // Phase B: one row per thread (tid<128) -> concurrent cursor atomics
    if (tid < 128) {
        int row = tid;
        int bi = bidx[row];
        size_t grow = bb + row;
        float md = fmaf(-2.f, bsc[row], xsqs[row]);  // dist = xsq - 2*best
        mind[grow] = md;
        argf[grow] = (float)bi;
        int pos = atomicAdd(&cursor[bi], 1);
        if (pos < cap) {
            rowlist[(size_t)bi * cap + pos] = (int)grow;
            fbflag[row] = 0;
        } else {
            fbflag[row] = 1;
        }
        #pragma unroll
        for (int m = 32; m; m >>= 1) md += __shfl_xor(md, m, 64);
        if (lane == 0) atomicAdd(&loss_part[(blockIdx.x * 2 + w) & 1023], md);
    }
    __syncthreads();

    // Phase C: Z = E[argmin] gather stream
    #pragma unroll 4
    for (int it = 0; it < 32; ++it) {
        int row = w * 32 + it;
        int bi = bidx[row];
        size_t grow = bb + row;
        float e = E[(size_t)bi * DD + lane];
        Z[grow * DD + lane] = e;
        if (fbflag[row]) {
            float x = X[grow * DD + lane];
            atomicAdd(&sumsFB[(size_t)bi * DD + lane], x);
        }
    }
}

// ---------------------------------------------------------------------------
// Segment sum + cs + loss + ma/E_new, fully fused. One 1024-thread block per
// code k: 16 waves split the row list.
// ---------------------------------------------------------------------------
__global__ __launch_bounds__(1024)
void vq_sum_ema(const float* __restrict__ X, const int* __restrict__ rowlist,
                const int* __restrict__ cursor, const float* __restrict__ sumsFB,
                const float* __restrict__ cluster_sizes,
                const float* __restrict__ loss_part, const float* __restrict__ mavg,
                float* __restrict__ o_ma, float* __restrict__ o_enew,
                float* __restrict__ o_cs, float* __restrict__ o_loss, int cap) {
    __shared__ float part[16][64];
    __shared__ float redt[16];
    int k = blockIdx.x;
    int lane = threadIdx.x & 63, w = threadIdx.x >> 6;

    // total = sum_j gamma*cluster_sizes[j] + (1-gamma)*counts[j]
    float t = GAMMA * cluster_sizes[threadIdx.x] + OMG * (float)cursor[threadIdx.x];
    #pragma unroll
    for (int m = 32; m; m >>= 1) t += __shfl_xor(t, m, 64);
    if (lane == 0) redt[w] = t;
    __syncthreads();
    float total = 0.f;
    #pragma unroll
    for (int j = 0; j < 16; ++j) total += redt[j];

    float csr = GAMMA * cluster_sizes[k] + OMG * (float)cursor[k];
    float cs = (csr + ALPHA) / (1.0f + (ALPHA * (float)KK) / total);
    if (threadIdx.x == 0) o_cs[k] = cs;

    if (k == 0) {   // loss finalize
        __syncthreads();
        float t2 = loss_part[threadIdx.x];
        #pragma unroll
        for (int m = 32; m; m >>= 1) t2 += __shfl_xor(t2, m, 64);
        if (lane == 0) redt[w] = t2;
        __syncthreads();
        if (threadIdx.x == 0) {
            float l = 0.f;
            #pragma unroll
            for (int j = 0; j < 16; ++j) l += redt[j];
            o_loss[0] = BETA * (l / (float)NN);
        }
    }

    // segment sum over this code's rows (atomic-free), 16 waves
    int cnt = cursor[k];
    int nr = cnt < cap ? cnt : cap;
    const int* rl = rowlist + (size_t)k * cap;
    float acc = 0.f;
    #pragma unroll 4
    for (int i = w; i < nr; i += 16) {
        int r = rl[i];
        acc += X[(size_t)r * DD + lane];
    }
    part[w][lane] = acc;
    __syncthreads();
    if (w == 0) {
        float s = sumsFB[(size_t)k * DD + lane];
        #pragma unroll
        for (int j = 0; j < 16; ++j) s += part[j][lane];
        float ma = GAMMA * mavg[(size_t)k * DD + lane] + OMG * s;
        o_ma[(size_t)k * DD + lane] = ma;
        o_enew[(size_t)k * DD + lane] = ma / cs;
    }
}

// ---------------------------------------------------------------------------
extern "C" void kernel_launch(void* const* d_in, const int* in_sizes, int n_in,
                              void* d_out, int out_size, void* d_ws, size_t ws_size,
                              hipStream_t stream) {
    const float* X = (const float*)d_in[0];
    const float* E = (const float*)d_in[1];
    const float* cluster_sizes = (const float*)d_in[2];
    const float* moving_avg = (const float*)d_in[3];

    // Output layout: Z[N*D], loss[1], argmins[N], min_dist[N],
    //                E_new[K*D], cs[K], ma[K*D]
    float* out = (float*)d_out;
    float* o_Z = out;
    float* o_loss = o_Z + (size_t)NN * DD;
    float* o_arg = o_loss + 1;
    float* o_mind = o_arg + NN;
    float* o_enew = o_mind + NN;
    float* o_cs = o_enew + (size_t)KK * DD;
    float* o_ma = o_cs + KK;

    // Workspace (4B units):
    // [cursor 1024 i32][loss_part 1024 f][sumsFB 65536 f][esqh 1024 f]
    // [Efrag 65536 f][rowlist K*cap i32]
    int* cursor = (int*)d_ws;
    float* loss_part = (float*)d_ws + 1024;
    float* sumsFB = loss_part + 1024;
    float* esqh = sumsFB + (size_t)KK * DD;
    float4* Efrag = (float4*)(esqh + KK);
    int* rowlist = (int*)(esqh + KK + (size_t)KK * DD);

    size_t base_bytes = (size_t)(1024 + 1024 + KK * DD + KK + KK * DD) * 4;
    long cap_l = ((long)ws_size - (long)base_bytes) / (long)(KK * sizeof(int));
    int cap = cap_l < 0 ? 0 : (cap_l > 1024 ? 1024 : (int)cap_l);

    // zero cursor + loss_part + sumsFB (contiguous prefix)
    hipMemsetAsync(d_ws, 0, (size_t)(1024 + 1024 + KK * DD) * 4, stream);

    vq_prep<<<KK / 16, 64, 0, stream>>>(E, Efrag, esqh);
    vq_main<<<NN / BM, 256, 0, stream>>>(X, E, Efrag, esqh, o_arg, o_mind, o_Z,
                                         cursor, rowlist, sumsFB, loss_part, cap);
    vq_sum_ema<<<KK, 1024, 0, stream>>>(X, rowlist, cursor, sumsFB, cluster_sizes,
                                        loss_part, moving_avg, o_ma, o_enew,
                                        o_cs, o_loss, cap);
}